// Round 5
// baseline (47.730 us; speedup 1.0000x reference)
//
#include <hip/hip_runtime.h>

// DynamicFiltering: out[b,c,y,x] = sum_{ki,kj} padded_img[b,c,y+ki,x+kj] * kernels[b,c,ki*3+kj,y,x]
// img: [B,C,H,W] f32; kernels: [B,C,9,H,W] f32; out: [B,C,H,W] f32. pad=1 (zeros).
// Memory-bound: mandatory traffic 277 MB (kernels 226.5 MB dominates).
// R4->R5: 4 output rows per thread (6-row img window) -> 2x in-flight kernel
// loads (ILP probe vs 6.3 TB/s copy ceiling; fills show 7.2 TB/s write rate).
// Keep chunked XCD swizzle (R4: +6%).

constexpr int B = 8, C = 3, H = 512, W = 512;
constexpr int W4 = W / 4;        // 128 float4 per row
constexpr int H4 = H / 4;        // 128 row-quads
constexpr int NBLK = B * C * H4 * W4 / 256;   // 1536 blocks
constexpr int NXCD = 8;
constexpr int BLK_PER_XCD = NBLK / NXCD;      // 192

typedef float floatx4 __attribute__((ext_vector_type(4)));

__global__ __launch_bounds__(256) void dynfilt_kernel(
    const float* __restrict__ img,
    const float* __restrict__ kern,
    float* __restrict__ out)
{
    // Chunked XCD swizzle: consecutive logical blocks (sharing halo rows /
    // same plane) land on the same XCD's L2.
    const int bid  = blockIdx.x;
    const int lbid = (bid & (NXCD - 1)) * BLK_PER_XCD + (bid >> 3);
    const int tid  = lbid * 256 + threadIdx.x;

    const int x4 = tid & (W4 - 1);           // 7 bits
    const int yq = (tid >> 7) & (H4 - 1);    // 7 bits
    const int bc = tid >> 14;                // / (W4*H4)
    const int x0 = x4 << 2;
    const int y0 = yq << 2;                  // 4 output rows y0..y0+3

    constexpr size_t plane = (size_t)H * W;
    const float* imgp = img + (size_t)bc * plane;

    // Image window: rows y0-1 .. y0+4 (6 rows), cols x0-1 .. x0+4 (6 cols).
    float win[6][6];
    #pragma unroll
    for (int r = 0; r < 6; ++r) {
        const int yy = y0 - 1 + r;
        if (yy < 0 || yy >= H) {             // only r==0 (y0==0) or r==5 (y0==H-4)
            #pragma unroll
            for (int j = 0; j < 6; ++j) win[r][j] = 0.0f;
        } else {
            const float* rowp = imgp + (size_t)yy * W + x0;
            const floatx4 v = *reinterpret_cast<const floatx4*>(rowp);
            win[r][1] = v.x; win[r][2] = v.y; win[r][3] = v.z; win[r][4] = v.w;
            win[r][0] = (x0 > 0)     ? rowp[-1] : 0.0f;
            win[r][5] = (x0 + 4 < W) ? rowp[4]  : 0.0f;
        }
    }

    const float* kernp = kern + (size_t)bc * 9 * plane + (size_t)y0 * W + x0;

    floatx4 acc[4] = {(floatx4)(0.0f), (floatx4)(0.0f), (floatx4)(0.0f), (floatx4)(0.0f)};
    #pragma unroll
    for (int ki = 0; ki < 3; ++ki) {
        #pragma unroll
        for (int kj = 0; kj < 3; ++kj) {
            const size_t koff = (size_t)(ki * 3 + kj) * plane;
            #pragma unroll
            for (int r = 0; r < 4; ++r) {
                const floatx4 kv = *reinterpret_cast<const floatx4*>(
                    kernp + koff + (size_t)r * W);
                acc[r].x = fmaf(win[ki + r][0 + kj], kv.x, acc[r].x);
                acc[r].y = fmaf(win[ki + r][1 + kj], kv.y, acc[r].y);
                acc[r].z = fmaf(win[ki + r][2 + kj], kv.z, acc[r].z);
                acc[r].w = fmaf(win[ki + r][3 + kj], kv.w, acc[r].w);
            }
        }
    }

    float* outp = out + (size_t)bc * plane + (size_t)y0 * W + x0;
    #pragma unroll
    for (int r = 0; r < 4; ++r)
        *reinterpret_cast<floatx4*>(outp + (size_t)r * W) = acc[r];
}

extern "C" void kernel_launch(void* const* d_in, const int* in_sizes, int n_in,
                              void* d_out, int out_size, void* d_ws, size_t ws_size,
                              hipStream_t stream)
{
    const float* img  = (const float*)d_in[0];
    const float* kern = (const float*)d_in[1];
    float* out = (float*)d_out;

    dynfilt_kernel<<<NBLK, 256, 0, stream>>>(img, kern, out);
}

// Round 6
// 46.030 us; speedup vs baseline: 1.0369x; 1.0369x over previous
//
#include <hip/hip_runtime.h>

// DynamicFiltering: out[b,c,y,x] = sum_{ki,kj} padded_img[b,c,y+ki,x+kj] * kernels[b,c,ki*3+kj,y,x]
// img: [B,C,H,W] f32; kernels: [B,C,9,H,W] f32; out: [B,C,H,W] f32. pad=1 (zeros).
// Memory-bound: mandatory traffic 277 MB (kernels 226.5 MB, zero reuse).
// FINAL (revert to R4 config — best measured, 46.4 us = ~6.1 TB/s achieved):
//   - float4 along W, 2 output rows per thread (4-row img window)
//   - chunked XCD swizzle (halo-sharing blocks on same XCD L2)  [+6%, R4]
// Rejected by measurement: nontemporal hints (R3, neutral), 4 rows/thread
// (R5, -3%: VGPR pressure/occupancy loss outweighs ILP gain).

constexpr int B = 8, C = 3, H = 512, W = 512;
constexpr int W4 = W / 4;        // 128 float4 per row
constexpr int H2 = H / 2;        // 256 row-pairs
constexpr int NBLK = B * C * H2 * W4 / 256;   // 3072 blocks
constexpr int NXCD = 8;
constexpr int BLK_PER_XCD = NBLK / NXCD;      // 384

typedef float floatx4 __attribute__((ext_vector_type(4)));

__global__ __launch_bounds__(256) void dynfilt_kernel(
    const float* __restrict__ img,
    const float* __restrict__ kern,
    float* __restrict__ out)
{
    // Chunked XCD swizzle: hw blocks round-robin across XCDs; remap so each
    // XCD owns a contiguous chunk of logical blocks (halo rows share L2).
    const int bid  = blockIdx.x;
    const int lbid = (bid & (NXCD - 1)) * BLK_PER_XCD + (bid >> 3);
    const int tid  = lbid * 256 + threadIdx.x;

    const int x4 = tid & (W4 - 1);           // 7 bits
    const int yh = (tid >> 7) & (H2 - 1);    // 8 bits
    const int bc = tid >> 15;                // / (W4*H2)
    const int x0 = x4 << 2;
    const int y0 = yh << 1;                  // even output row; also does y0+1

    constexpr size_t plane = (size_t)H * W;
    const float* imgp = img + (size_t)bc * plane;

    // Image window: rows y0-1 .. y0+2 (4 rows), cols x0-1 .. x0+4 (6 cols).
    float win[4][6];
    #pragma unroll
    for (int r = 0; r < 4; ++r) {
        const int yy = y0 - 1 + r;
        if (yy < 0 || yy >= H) {             // only r==0 (y0==0) or r==3 (y0==H-2)
            #pragma unroll
            for (int j = 0; j < 6; ++j) win[r][j] = 0.0f;
        } else {
            const float* rowp = imgp + (size_t)yy * W + x0;
            const floatx4 v = *reinterpret_cast<const floatx4*>(rowp);
            win[r][1] = v.x; win[r][2] = v.y; win[r][3] = v.z; win[r][4] = v.w;
            win[r][0] = (x0 > 0)     ? rowp[-1] : 0.0f;
            win[r][5] = (x0 + 4 < W) ? rowp[4]  : 0.0f;
        }
    }

    const float* kernp0 = kern + (size_t)bc * 9 * plane + (size_t)y0 * W + x0;
    const float* kernp1 = kernp0 + W;

    floatx4 acc0 = (floatx4)(0.0f);
    floatx4 acc1 = (floatx4)(0.0f);
    #pragma unroll
    for (int ki = 0; ki < 3; ++ki) {
        #pragma unroll
        for (int kj = 0; kj < 3; ++kj) {
            const size_t koff = (size_t)(ki * 3 + kj) * plane;
            const floatx4 kv0 = *reinterpret_cast<const floatx4*>(kernp0 + koff);
            const floatx4 kv1 = *reinterpret_cast<const floatx4*>(kernp1 + koff);
            // output row y0 uses window rows ki; row y0+1 uses ki+1
            acc0.x = fmaf(win[ki    ][0 + kj], kv0.x, acc0.x);
            acc0.y = fmaf(win[ki    ][1 + kj], kv0.y, acc0.y);
            acc0.z = fmaf(win[ki    ][2 + kj], kv0.z, acc0.z);
            acc0.w = fmaf(win[ki    ][3 + kj], kv0.w, acc0.w);
            acc1.x = fmaf(win[ki + 1][0 + kj], kv1.x, acc1.x);
            acc1.y = fmaf(win[ki + 1][1 + kj], kv1.y, acc1.y);
            acc1.z = fmaf(win[ki + 1][2 + kj], kv1.z, acc1.z);
            acc1.w = fmaf(win[ki + 1][3 + kj], kv1.w, acc1.w);
        }
    }

    float* outp = out + (size_t)bc * plane + (size_t)y0 * W + x0;
    *reinterpret_cast<floatx4*>(outp)     = acc0;
    *reinterpret_cast<floatx4*>(outp + W) = acc1;
}

extern "C" void kernel_launch(void* const* d_in, const int* in_sizes, int n_in,
                              void* d_out, int out_size, void* d_ws, size_t ws_size,
                              hipStream_t stream)
{
    const float* img  = (const float*)d_in[0];
    const float* kern = (const float*)d_in[1];
    float* out = (float*)d_out;

    dynfilt_kernel<<<NBLK, 256, 0, stream>>>(img, kern, out);
}